// Round 23
// baseline (481.892 us; speedup 1.0000x reference)
//
#include <hip/hip_runtime.h>
#include <hip/hip_cooperative_groups.h>

namespace cg = cooperative_groups;

typedef __attribute__((ext_vector_type(8))) short bhalf8;
typedef __attribute__((ext_vector_type(4))) float floatx4;

// ---- device-global scratch ----
__device__ unsigned short g_whh[3072*768];     // bf16 W_hh
__device__ unsigned short g_wih[3072*768];     // bf16 W_ih
__device__ unsigned short g_wcln[1536*768];    // bf16 [Ww;Wb]
__device__ unsigned short g_whl[128*768];      // bf16 [Wh;Wt;pad]
__device__ unsigned short g_h2[2*64*768];      // bf16 h ping-pong
__device__ float g_xg[1024*3072];              // f32 xgates
__device__ float g_wv[64*768], g_bv[64*768];   // f32 CLN w,b
__device__ float g_bias[3072];                 // b_ih + b_hh
__device__ float g_cw[768], g_cb[768];
__device__ float g_bh[64], g_bt[64];

static __device__ __forceinline__ unsigned short f2bf(float f){
  unsigned u = __builtin_bit_cast(unsigned, f);
  u = (u + 0x7FFFu + ((u >> 16) & 1u)) >> 16;
  return (unsigned short)u;
}
static __device__ __forceinline__ float sigm(float x){ return 1.0f/(1.0f + __expf(-x)); }
static __device__ __forceinline__ float tanhq(float x){ float e = __expf(-2.0f*x); return (1.0f - e)/(1.0f + e); }

static __device__ __forceinline__ void cv8(const float* __restrict__ s, unsigned short* __restrict__ d){
  float4 a = ((const float4*)s)[0];
  float4 b = ((const float4*)s)[1];
  uint4 v;
  v.x = (unsigned)f2bf(a.x) | ((unsigned)f2bf(a.y) << 16);
  v.y = (unsigned)f2bf(a.z) | ((unsigned)f2bf(a.w) << 16);
  v.z = (unsigned)f2bf(b.x) | ((unsigned)f2bf(b.y) << 16);
  v.w = (unsigned)f2bf(b.z) | ((unsigned)f2bf(b.w) << 16);
  *(uint4*)d = v;
}

// ---------------- K0: vectorized weight conversions + init ----------------
__global__ __launch_bounds__(256) void casrel_prep(
    const float* __restrict__ W_ih, const float* __restrict__ W_hh,
    const float* __restrict__ Ww,   const float* __restrict__ Wb,
    const float* __restrict__ Wh,   const float* __restrict__ Wt,
    const float* __restrict__ b_ih, const float* __restrict__ b_hh,
    const float* __restrict__ cw,   const float* __restrict__ cb,
    const float* __restrict__ bh,   const float* __restrict__ bt){
  const long CW = 294912;            // 3072*768/8
  const long CC = 147456;            // 1536*768/8
  const long CL = 12288;             // 128*768/8
  const long CH = 12288;             // 2*64*768/8
  const long CB = 384;               // 3072/8
  const long CV = 96;                // 768/8
  const long CR = 8;                 // 64/8
  const long total = CW*2 + CC + CL + CH + CB + CV*2 + CR*2;
  for(long i = (long)blockIdx.x*256 + threadIdx.x; i < total; i += (long)gridDim.x*256){
    long j = i;
    if(j < CW){ cv8(W_hh + j*8, g_whh + j*8); continue; } j -= CW;
    if(j < CW){ cv8(W_ih + j*8, g_wih + j*8); continue; } j -= CW;
    if(j < CC){ long e = j*8;
                if(e < 589824) cv8(Ww + e, g_wcln + e);
                else           cv8(Wb + (e - 589824), g_wcln + e);
                continue; } j -= CC;
    if(j < CL){ long e = j*8;
                long r = e / 768, k = e - r*768;
                if(r < 51)       cv8(Wh + r*768 + k, g_whl + e);
                else if(r < 102) cv8(Wt + (r-51)*768 + k, g_whl + e);
                else             *(uint4*)(g_whl + e) = make_uint4(0,0,0,0);
                continue; } j -= CL;
    if(j < CH){ *(uint4*)(g_h2 + j*8) = make_uint4(0,0,0,0); continue; } j -= CH;
    if(j < CB){ long e = j*8;
                #pragma unroll
                for(int q=0;q<8;q++) g_bias[e+q] = b_ih[e+q] + b_hh[e+q];
                continue; } j -= CB;
    if(j < CV){ long e = j*8;
                *(float4*)(g_cw + e)     = *(const float4*)(cw + e);
                *(float4*)(g_cw + e + 4) = *(const float4*)(cw + e + 4);
                continue; } j -= CV;
    if(j < CV){ long e = j*8;
                *(float4*)(g_cb + e)     = *(const float4*)(cb + e);
                *(float4*)(g_cb + e + 4) = *(const float4*)(cb + e + 4);
                continue; } j -= CV;
    if(j < CR){ long e = j*8;
                #pragma unroll
                for(int q=0;q<8;q++){ long n = e+q; g_bh[n] = (n < 51) ? bh[n] : 0.0f; }
                continue; } j -= CR;
    { long e = j*8;
      #pragma unroll
      for(int q=0;q<8;q++){ long n = e+q; g_bt[n] = (n < 51) ? bt[n] : 0.0f; } }
  }
}

// ---------------- K1: xgates = gather(embed) @ W_ih^T + (b_ih + b_hh) ----------------
__global__ __launch_bounds__(256) void casrel_xgates(
    const float* __restrict__ embed, const int* __restrict__ head){
  __shared__ char sB[128*128];
  const int tid = threadIdx.x, l = tid & 63, w = tid >> 6;
  const int n0 = blockIdx.x * 128;
  const int m0 = blockIdx.y * 64 + w*16;
  const int mrow = m0 + (l & 15);
  const int b = mrow >> 4, t = mrow & 15;
  int pos = head[b] + t; pos = pos < 0 ? 0 : (pos > 511 ? 511 : pos);
  const float* aptr = embed + ((long)b*512 + pos)*768 + ((l >> 4)*8);
  floatx4 acc[8];
  #pragma unroll
  for(int q=0;q<8;q++){ acc[q][0]=0.f; acc[q][1]=0.f; acc[q][2]=0.f; acc[q][3]=0.f; }
  for(int kt=0; kt<12; ++kt){
    __syncthreads();
    #pragma unroll
    for(int j=0;j<4;j++){
      int f = tid + 256*j;
      int row = f >> 3, seg = f & 7;
      uint4 v = *(const uint4*)(g_wih + ((long)(n0+row))*768 + kt*64 + seg*8);
      *(uint4*)(sB + row*128 + ((seg*16) ^ ((row & 7) << 4))) = v;
    }
    __syncthreads();
    #pragma unroll
    for(int ks=0; ks<2; ++ks){
      const int k = kt*64 + ks*32;
      float4 lo = *(const float4*)(aptr + k);
      float4 hi = *(const float4*)(aptr + k + 4);
      bhalf8 a;
      a[0]=(short)f2bf(lo.x); a[1]=(short)f2bf(lo.y); a[2]=(short)f2bf(lo.z); a[3]=(short)f2bf(lo.w);
      a[4]=(short)f2bf(hi.x); a[5]=(short)f2bf(hi.y); a[6]=(short)f2bf(hi.z); a[7]=(short)f2bf(hi.w);
      const int kb = ks*64 + ((l >> 4)*16);
      #pragma unroll
      for(int q=0;q<8;q++){
        int row = q*16 + (l & 15);
        bhalf8 bb = *(const bhalf8*)(sB + row*128 + (kb ^ ((row & 7) << 4)));
        acc[q] = __builtin_amdgcn_mfma_f32_16x16x32_bf16(a, bb, acc[q], 0, 0, 0);
      }
    }
  }
  #pragma unroll
  for(int q=0;q<8;q++){
    const int n = n0 + q*16 + (l & 15);
    const float bias = g_bias[n];
    #pragma unroll
    for(int r=0;r<4;r++){
      const int m = m0 + (l >> 4)*4 + r;
      g_xg[(long)m*3072 + n] = acc[q][r] + bias;
    }
  }
}

// ---------------- K2: cooperative 16-step LSTM + CLN projection tail ----------------
// 48 blocks; block bk owns h-cols [bk*16, bk*16+16) across all 4 gates.
// W_hh slice staged ONCE (96 KB LDS); c in registers; h ping-pong in global; 1 grid.sync/step.
__global__ __launch_bounds__(256) void casrel_lstm(
    const int* __restrict__ head, const int* __restrict__ tail){
  __shared__ char sW[64*1536];                       // 64 rows x 768 bf16, swizzled
  cg::grid_group grid = cg::this_grid();
  const int tid = threadIdx.x, l = tid & 63, w = tid >> 6;
  const int j0 = blockIdx.x * 16;
  #pragma unroll 4
  for(int j=0;j<24;j++){                             // one-time W_hh slice stage (6144 x 16B)
    int f = tid + 256*j;
    int row = f / 96, seg = f - row*96;
    int grow = (row >> 4)*768 + j0 + (row & 15);
    uint4 v = *(const uint4*)(g_whh + (long)grow*768 + seg*8);
    *(uint4*)(sW + row*1536 + ((seg*16) ^ ((row & 7) << 4))) = v;
  }
  __syncthreads();
  float creg[4];
  int spown[4];
  #pragma unroll
  for(int r=0;r<4;r++){
    int b = w*16 + (l >> 4)*4 + r;
    spown[r] = tail[b] - head[b];
    creg[r] = 0.f;
  }
  const int jown = j0 + (l & 15);
  const int arow = w*16 + (l & 15);
  for(int t=0;t<16;t++){
    const unsigned short* hin = g_h2 + (t & 1)*49152;
    unsigned short* hout = g_h2 + ((t & 1) ^ 1)*49152;
    floatx4 acc[4];
    #pragma unroll
    for(int g=0;g<4;g++){ acc[g][0]=0.f; acc[g][1]=0.f; acc[g][2]=0.f; acc[g][3]=0.f; }
    const unsigned short* ap = hin + arow*768 + ((l >> 4)*8);
    #pragma unroll 6
    for(int ks=0; ks<24; ++ks){
      bhalf8 a = *(const bhalf8*)(ap + ks*32);
      const int kb = ks*64 + ((l >> 4)*16);
      #pragma unroll
      for(int g=0;g<4;g++){
        int row = g*16 + (l & 15);
        bhalf8 bb = *(const bhalf8*)(sW + row*1536 + (kb ^ ((row & 7) << 4)));
        acc[g] = __builtin_amdgcn_mfma_f32_16x16x32_bf16(a, bb, acc[g], 0, 0, 0);
      }
    }
    #pragma unroll
    for(int r=0;r<4;r++){
      const int b = w*16 + (l >> 4)*4 + r;
      const float* xp = g_xg + ((long)(b*16 + t))*3072 + jown;
      float Gi = acc[0][r] + xp[0];
      float Gf = acc[1][r] + xp[768];
      float Gg = acc[2][r] + xp[1536];
      float Go = acc[3][r] + xp[2304];
      unsigned short hv;
      if(t <= spown[r]){
        float ig = sigm(Gi), fg = sigm(Gf), gg = tanhq(Gg), og = sigm(Go);
        creg[r] = fg*creg[r] + ig*gg;
        hv = f2bf(og*tanhq(creg[r]));
      } else {
        hv = hin[b*768 + jown];
      }
      hout[b*768 + jown] = hv;
    }
    __threadfence();
    grid.sync();
  }
  // ---- tail: wv = hn@Ww^T + cw ; bv = hn@Wb^T + cb  (hn = g_h2 buf 0) ----
  __syncthreads();
  const int n0c = blockIdx.x * 32;
  #pragma unroll 4
  for(int j=0;j<12;j++){
    int f = tid + 256*j;
    int row = f / 96, seg = f - row*96;
    uint4 v = *(const uint4*)(g_wcln + (long)(n0c+row)*768 + seg*8);
    *(uint4*)(sW + row*1536 + ((seg*16) ^ ((row & 7) << 4))) = v;
  }
  __syncthreads();
  floatx4 acc2[2];
  #pragma unroll
  for(int q=0;q<2;q++){ acc2[q][0]=0.f; acc2[q][1]=0.f; acc2[q][2]=0.f; acc2[q][3]=0.f; }
  const unsigned short* ap2 = g_h2 + arow*768 + ((l >> 4)*8);
  for(int ks=0; ks<24; ++ks){
    bhalf8 a = *(const bhalf8*)(ap2 + ks*32);
    const int kb = ks*64 + ((l >> 4)*16);
    #pragma unroll
    for(int q=0;q<2;q++){
      int row = q*16 + (l & 15);
      bhalf8 bb = *(const bhalf8*)(sW + row*1536 + (kb ^ ((row & 7) << 4)));
      acc2[q] = __builtin_amdgcn_mfma_f32_16x16x32_bf16(a, bb, acc2[q], 0, 0, 0);
    }
  }
  #pragma unroll
  for(int q=0;q<2;q++){
    const int n = n0c + q*16 + (l & 15);
    #pragma unroll
    for(int r=0;r<4;r++){
      const int b = w*16 + (l >> 4)*4 + r;
      float v = acc2[q][r];
      if(n < 768) g_wv[b*768 + n] = v + g_cw[n];
      else        g_bv[b*768 + (n - 768)] = v + g_cb[n - 768];
    }
  }
}

// ---------------- K3: fused cond-LN + heads/tails, barrier-free main loop ----------------
__global__ __launch_bounds__(256) void casrel_out(
    const float* __restrict__ embed, float* __restrict__ out){
  __shared__ float sMu[32], sRs[32];
  const int tid = threadIdx.x, l = tid & 63, w = tid >> 6;
  const int b = blockIdx.y;
  const int s0 = blockIdx.x * 32;
  const float* xbase = embed + ((long)b*512 + s0)*768;
  for(int rr=0; rr<8; ++rr){                         // wave-per-row stats
    const int row = w*8 + rr;
    const float* rp = xbase + row*768;
    float sm = 0.f, sq = 0.f;
    #pragma unroll
    for(int q=0;q<3;q++){
      float4 v = *(const float4*)(rp + l*4 + q*256);
      sm += v.x + v.y + v.z + v.w;
      sq += v.x*v.x + v.y*v.y + v.z*v.z + v.w*v.w;
    }
    #pragma unroll
    for(int o=32;o>0;o>>=1){ sm += __shfl_xor(sm, o); sq += __shfl_xor(sq, o); }
    if(l == 0){
      float mu = sm * (1.0f/768.0f);
      float var = sq * (1.0f/768.0f) - mu*mu;
      sMu[row] = mu;
      sRs[row] = 1.0f/(sqrtf(var + 1e-12f) + 1e-12f);
    }
  }
  __syncthreads();
  const int mf = w >> 1, nb = (w & 1)*4;             // wave -> (16-row half, col group)
  const int lrow = mf*16 + (l & 15);
  const float mu = sMu[lrow], rs = sRs[lrow];
  const float* aeb = embed + ((long)b*512 + s0 + lrow)*768;   // this lane's A row
  const float* wvb = g_wv + b*768;
  const float* bvb = g_bv + b*768;
  floatx4 acc[4];
  #pragma unroll
  for(int q=0;q<4;q++){ acc[q][0]=0.f; acc[q][1]=0.f; acc[q][2]=0.f; acc[q][3]=0.f; }
  for(int ks=0; ks<24; ++ks){
    const int k = ks*32 + ((l >> 4)*8);
    float4 xlo = *(const float4*)(aeb + k);
    float4 xhi = *(const float4*)(aeb + k + 4);
    float4 wlo = *(const float4*)(wvb + k);
    float4 whi = *(const float4*)(wvb + k + 4);
    float4 clo = *(const float4*)(bvb + k);
    float4 chi = *(const float4*)(bvb + k + 4);
    bhalf8 a;
    a[0]=(short)f2bf((xlo.x - mu)*rs*wlo.x + clo.x);
    a[1]=(short)f2bf((xlo.y - mu)*rs*wlo.y + clo.y);
    a[2]=(short)f2bf((xlo.z - mu)*rs*wlo.z + clo.z);
    a[3]=(short)f2bf((xlo.w - mu)*rs*wlo.w + clo.w);
    a[4]=(short)f2bf((xhi.x - mu)*rs*whi.x + chi.x);
    a[5]=(short)f2bf((xhi.y - mu)*rs*whi.y + chi.y);
    a[6]=(short)f2bf((xhi.z - mu)*rs*whi.z + chi.z);
    a[7]=(short)f2bf((xhi.w - mu)*rs*whi.w + chi.w);
    #pragma unroll
    for(int q=0;q<4;q++){
      const int row = (nb + q)*16 + (l & 15);
      bhalf8 bb = *(const bhalf8*)(g_whl + (long)row*768 + k);
      acc[q] = __builtin_amdgcn_mfma_f32_16x16x32_bf16(a, bb, acc[q], 0, 0, 0);
    }
  }
  const long HT = (long)64*512*51;
  #pragma unroll
  for(int q=0;q<4;q++){
    const int n = (nb + q)*16 + (l & 15);
    if(n >= 102) continue;
    const int rr = (n < 51) ? n : (n - 51);
    const long obase = (n < 51) ? 0 : HT;
    const float bias = (n < 51) ? g_bh[n] : g_bt[n - 51];
    #pragma unroll
    for(int r=0;r<4;r++){
      const int s = s0 + mf*16 + (l >> 4)*4 + r;
      out[obase + ((long)b*512 + s)*51 + rr] = sigm(acc[q][r] + bias);
    }
  }
}

extern "C" void kernel_launch(void* const* d_in, const int* in_sizes, int n_in,
                              void* d_out, int out_size, void* d_ws, size_t ws_size,
                              hipStream_t stream){
  const float* embed = (const float*)d_in[0];
  const int*   head  = (const int*)d_in[1];
  const int*   tail  = (const int*)d_in[2];
  const float* W_ih  = (const float*)d_in[3];
  const float* W_hh  = (const float*)d_in[4];
  const float* b_ih  = (const float*)d_in[5];
  const float* b_hh  = (const float*)d_in[6];
  const float* cw    = (const float*)d_in[7];
  const float* cb    = (const float*)d_in[8];
  const float* Ww    = (const float*)d_in[9];
  const float* Wb    = (const float*)d_in[10];
  const float* Wh    = (const float*)d_in[11];
  const float* bh    = (const float*)d_in[12];
  const float* Wt    = (const float*)d_in[13];
  const float* bt    = (const float*)d_in[14];
  float* out = (float*)d_out;
  (void)d_ws; (void)ws_size;

  casrel_prep<<<dim3(2048), dim3(256), 0, stream>>>(W_ih, W_hh, Ww, Wb, Wh, Wt,
                                                    b_ih, b_hh, cw, cb, bh, bt);
  casrel_xgates<<<dim3(24,16), dim3(256), 0, stream>>>(embed, head);
  {
    void* args[] = {(void*)&head, (void*)&tail};
    hipLaunchCooperativeKernel((void*)casrel_lstm, dim3(48), dim3(256), args, 0, stream);
  }
  casrel_out<<<dim3(16,64), dim3(256), 0, stream>>>(embed, out);
}

// Round 24
// 325.629 us; speedup vs baseline: 1.4799x; 1.4799x over previous
//
#include <hip/hip_runtime.h>

typedef __attribute__((ext_vector_type(8))) short bhalf8;
typedef __attribute__((ext_vector_type(4))) float floatx4;

// ---- device-global scratch ----
__device__ unsigned short g_whh[3072*768];     // bf16 W_hh
__device__ unsigned short g_wih[3072*768];     // bf16 W_ih
__device__ unsigned short g_wcln[1536*768];    // bf16 [Ww;Wb]
__device__ unsigned short g_whl[128*768];      // bf16 [Wh;Wt;pad]
__device__ unsigned short g_h2[2*64*768];      // bf16 h ping-pong
__device__ float g_cbuf[64*768];               // f32 c
__device__ float g_xg[16*64*3072];             // f32 xgates, STEP-MAJOR [t][b][3072]
__device__ float g_wv[64*768], g_bv[64*768];   // f32 CLN w,b
__device__ float g_bias[3072];                 // b_ih + b_hh
__device__ float g_cw[768], g_cb[768];
__device__ float g_bh[64], g_bt[64];

static __device__ __forceinline__ unsigned short f2bf(float f){
  unsigned u = __builtin_bit_cast(unsigned, f);
  u = (u + 0x7FFFu + ((u >> 16) & 1u)) >> 16;
  return (unsigned short)u;
}
static __device__ __forceinline__ float sigm(float x){ return 1.0f/(1.0f + __expf(-x)); }
static __device__ __forceinline__ float tanhq(float x){ float e = __expf(-2.0f*x); return (1.0f - e)/(1.0f + e); }

static __device__ __forceinline__ void cv8(const float* __restrict__ s, unsigned short* __restrict__ d){
  float4 a = ((const float4*)s)[0];
  float4 b = ((const float4*)s)[1];
  uint4 v;
  v.x = (unsigned)f2bf(a.x) | ((unsigned)f2bf(a.y) << 16);
  v.y = (unsigned)f2bf(a.z) | ((unsigned)f2bf(a.w) << 16);
  v.z = (unsigned)f2bf(b.x) | ((unsigned)f2bf(b.y) << 16);
  v.w = (unsigned)f2bf(b.z) | ((unsigned)f2bf(b.w) << 16);
  *(uint4*)d = v;
}

// ---------------- K0: vectorized weight conversions + init ----------------
__global__ __launch_bounds__(256) void casrel_prep(
    const float* __restrict__ W_ih, const float* __restrict__ W_hh,
    const float* __restrict__ Ww,   const float* __restrict__ Wb,
    const float* __restrict__ Wh,   const float* __restrict__ Wt,
    const float* __restrict__ b_ih, const float* __restrict__ b_hh,
    const float* __restrict__ cw,   const float* __restrict__ cb,
    const float* __restrict__ bh,   const float* __restrict__ bt){
  const long CW = 294912;            // 3072*768/8
  const long CC = 147456;            // 1536*768/8
  const long CL = 12288;             // 128*768/8
  const long CH = 12288;             // 2*64*768/8
  const long CF = 6144;              // 64*768/8 (cbuf f32)
  const long CB = 384, CV = 96, CR = 8;
  const long total = CW*2 + CC + CL + CH + CF + CB + CV*2 + CR*2;
  for(long i = (long)blockIdx.x*256 + threadIdx.x; i < total; i += (long)gridDim.x*256){
    long j = i;
    if(j < CW){ cv8(W_hh + j*8, g_whh + j*8); continue; } j -= CW;
    if(j < CW){ cv8(W_ih + j*8, g_wih + j*8); continue; } j -= CW;
    if(j < CC){ long e = j*8;
                if(e < 589824) cv8(Ww + e, g_wcln + e);
                else           cv8(Wb + (e - 589824), g_wcln + e);
                continue; } j -= CC;
    if(j < CL){ long e = j*8;
                long r = e / 768, k = e - r*768;
                if(r < 51)       cv8(Wh + r*768 + k, g_whl + e);
                else if(r < 102) cv8(Wt + (r-51)*768 + k, g_whl + e);
                else             *(uint4*)(g_whl + e) = make_uint4(0,0,0,0);
                continue; } j -= CL;
    if(j < CH){ *(uint4*)(g_h2 + j*8) = make_uint4(0,0,0,0); continue; } j -= CH;
    if(j < CF){ long e = j*8;
                *(float4*)(g_cbuf + e)     = make_float4(0,0,0,0);
                *(float4*)(g_cbuf + e + 4) = make_float4(0,0,0,0);
                continue; } j -= CF;
    if(j < CB){ long e = j*8;
                #pragma unroll
                for(int q=0;q<8;q++) g_bias[e+q] = b_ih[e+q] + b_hh[e+q];
                continue; } j -= CB;
    if(j < CV){ long e = j*8;
                *(float4*)(g_cw + e)     = *(const float4*)(cw + e);
                *(float4*)(g_cw + e + 4) = *(const float4*)(cw + e + 4);
                continue; } j -= CV;
    if(j < CV){ long e = j*8;
                *(float4*)(g_cb + e)     = *(const float4*)(cb + e);
                *(float4*)(g_cb + e + 4) = *(const float4*)(cb + e + 4);
                continue; } j -= CV;
    if(j < CR){ long e = j*8;
                #pragma unroll
                for(int q=0;q<8;q++){ long n = e+q; g_bh[n] = (n < 51) ? bh[n] : 0.0f; }
                continue; } j -= CR;
    { long e = j*8;
      #pragma unroll
      for(int q=0;q<8;q++){ long n = e+q; g_bt[n] = (n < 51) ? bt[n] : 0.0f; } }
  }
}

// ---------------- K1: xgates -> STEP-MAJOR layout [t][b][3072] ----------------
__global__ __launch_bounds__(256) void casrel_xgates(
    const float* __restrict__ embed, const int* __restrict__ head){
  __shared__ char sB[128*128];
  const int tid = threadIdx.x, l = tid & 63, w = tid >> 6;
  const int n0 = blockIdx.x * 128;
  const int m0 = blockIdx.y * 64 + w*16;
  const int mrow = m0 + (l & 15);
  const int b = mrow >> 4, t = mrow & 15;
  int pos = head[b] + t; pos = pos < 0 ? 0 : (pos > 511 ? 511 : pos);
  const float* aptr = embed + ((long)b*512 + pos)*768 + ((l >> 4)*8);
  floatx4 acc[8];
  #pragma unroll
  for(int q=0;q<8;q++){ acc[q][0]=0.f; acc[q][1]=0.f; acc[q][2]=0.f; acc[q][3]=0.f; }
  for(int kt=0; kt<12; ++kt){
    __syncthreads();
    #pragma unroll
    for(int j=0;j<4;j++){
      int f = tid + 256*j;
      int row = f >> 3, seg = f & 7;
      uint4 v = *(const uint4*)(g_wih + ((long)(n0+row))*768 + kt*64 + seg*8);
      *(uint4*)(sB + row*128 + ((seg*16) ^ ((row & 7) << 4))) = v;
    }
    __syncthreads();
    #pragma unroll
    for(int ks=0; ks<2; ++ks){
      const int k = kt*64 + ks*32;
      float4 lo = *(const float4*)(aptr + k);
      float4 hi = *(const float4*)(aptr + k + 4);
      bhalf8 a;
      a[0]=(short)f2bf(lo.x); a[1]=(short)f2bf(lo.y); a[2]=(short)f2bf(lo.z); a[3]=(short)f2bf(lo.w);
      a[4]=(short)f2bf(hi.x); a[5]=(short)f2bf(hi.y); a[6]=(short)f2bf(hi.z); a[7]=(short)f2bf(hi.w);
      const int kb = ks*64 + ((l >> 4)*16);
      #pragma unroll
      for(int q=0;q<8;q++){
        int row = q*16 + (l & 15);
        bhalf8 bb = *(const bhalf8*)(sB + row*128 + (kb ^ ((row & 7) << 4)));
        acc[q] = __builtin_amdgcn_mfma_f32_16x16x32_bf16(a, bb, acc[q], 0, 0, 0);
      }
    }
  }
  #pragma unroll
  for(int q=0;q<8;q++){
    const int n = n0 + q*16 + (l & 15);
    const float bias = g_bias[n];
    #pragma unroll
    for(int r=0;r<4;r++){
      const int m = m0 + (l >> 4)*4 + r;
      const int bb2 = m >> 4, tt = m & 15;
      g_xg[((long)(tt*64 + bb2))*3072 + n] = acc[q][r] + bias;
    }
  }
}

// ---------------- K2a: one LSTM step (16 stream-ordered launches) ----------------
__global__ __launch_bounds__(256) void casrel_step(
    const int* __restrict__ head, const int* __restrict__ tail, int t){
  __shared__ char sW[64*768];
  const unsigned short* hin = g_h2 + (t & 1)*49152;
  unsigned short* hout = g_h2 + ((t & 1) ^ 1)*49152;
  const int tid = threadIdx.x, l = tid & 63, w = tid >> 6;
  const int j0 = blockIdx.x * 16;
  const int jown = j0 + (l & 15);
  const int arow = w*16 + (l & 15);
  floatx4 acc[4];
  #pragma unroll
  for(int g=0;g<4;g++){ acc[g][0]=0.f; acc[g][1]=0.f; acc[g][2]=0.f; acc[g][3]=0.f; }
  for(int kt=0; kt<2; ++kt){
    __syncthreads();
    #pragma unroll
    for(int j=0;j<12;j++){
      int f = tid + 256*j;
      int row = f / 48, seg = f - row*48;
      int grow = (row >> 4)*768 + j0 + (row & 15);
      uint4 v = *(const uint4*)(g_whh + (long)grow*768 + kt*384 + seg*8);
      *(uint4*)(sW + row*768 + ((seg*16) ^ ((row & 7) << 4))) = v;
    }
    __syncthreads();
    const unsigned short* ap = hin + arow*768 + kt*384 + ((l >> 4)*8);
    #pragma unroll 4
    for(int ks=0; ks<12; ++ks){
      bhalf8 a = *(const bhalf8*)(ap + ks*32);
      const int kb = ks*64 + ((l >> 4)*16);
      #pragma unroll
      for(int g=0;g<4;g++){
        int row = g*16 + (l & 15);
        bhalf8 bb = *(const bhalf8*)(sW + row*768 + (kb ^ ((row & 7) << 4)));
        acc[g] = __builtin_amdgcn_mfma_f32_16x16x32_bf16(a, bb, acc[g], 0, 0, 0);
      }
    }
  }
  #pragma unroll
  for(int r=0;r<4;r++){
    const int b = w*16 + (l >> 4)*4 + r;
    const int cell = b*768 + jown;
    const float* xp = g_xg + ((long)(t*64 + b))*3072 + jown;   // step-major
    float Gi = acc[0][r] + xp[0];
    float Gf = acc[1][r] + xp[768];
    float Gg = acc[2][r] + xp[1536];
    float Go = acc[3][r] + xp[2304];
    if(t <= tail[b] - head[b]){
      float c = g_cbuf[cell];
      float ig = sigm(Gi), fg = sigm(Gf), gg = tanhq(Gg), og = sigm(Go);
      c = fg*c + ig*gg;
      g_cbuf[cell] = c;
      hout[cell] = f2bf(og*tanhq(c));
    } else {
      hout[cell] = hin[cell];
    }
  }
}

// ---------------- K2b: wv = hn@Ww^T + cw ; bv = hn@Wb^T + cb ----------------
__global__ __launch_bounds__(256) void casrel_clnproj(){
  __shared__ char sW[32*1536];
  const int tid = threadIdx.x, l = tid & 63, w = tid >> 6;
  const int n0c = blockIdx.x * 32;
  #pragma unroll
  for(int j=0;j<12;j++){
    int f = tid + 256*j;
    int row = f / 96, seg = f - row*96;
    uint4 v = *(const uint4*)(g_wcln + (long)(n0c+row)*768 + seg*8);
    *(uint4*)(sW + row*1536 + ((seg*16) ^ ((row & 7) << 4))) = v;
  }
  __syncthreads();
  const int arow = w*16 + (l & 15);
  floatx4 acc2[2];
  #pragma unroll
  for(int q=0;q<2;q++){ acc2[q][0]=0.f; acc2[q][1]=0.f; acc2[q][2]=0.f; acc2[q][3]=0.f; }
  const unsigned short* ap2 = g_h2 + arow*768 + ((l >> 4)*8);   // buf 0 = final h
  for(int ks=0; ks<24; ++ks){
    bhalf8 a = *(const bhalf8*)(ap2 + ks*32);
    const int kb = ks*64 + ((l >> 4)*16);
    #pragma unroll
    for(int q=0;q<2;q++){
      int row = q*16 + (l & 15);
      bhalf8 bb = *(const bhalf8*)(sW + row*1536 + (kb ^ ((row & 7) << 4)));
      acc2[q] = __builtin_amdgcn_mfma_f32_16x16x32_bf16(a, bb, acc2[q], 0, 0, 0);
    }
  }
  #pragma unroll
  for(int q=0;q<2;q++){
    const int n = n0c + q*16 + (l & 15);
    #pragma unroll
    for(int r=0;r<4;r++){
      const int b = w*16 + (l >> 4)*4 + r;
      float v = acc2[q][r];
      if(n < 768) g_wv[b*768 + n] = v + g_cw[n];
      else        g_bv[b*768 + (n - 768)] = v + g_cb[n - 768];
    }
  }
}

// ---------------- K3: fused cond-LN + heads/tails, barrier-free main loop ----------------
__global__ __launch_bounds__(256) void casrel_out(
    const float* __restrict__ embed, float* __restrict__ out){
  __shared__ float sMu[32], sRs[32];
  const int tid = threadIdx.x, l = tid & 63, w = tid >> 6;
  const int b = blockIdx.y;
  const int s0 = blockIdx.x * 32;
  const float* xbase = embed + ((long)b*512 + s0)*768;
  for(int rr=0; rr<8; ++rr){                         // wave-per-row stats
    const int row = w*8 + rr;
    const float* rp = xbase + row*768;
    float sm = 0.f, sq = 0.f;
    #pragma unroll
    for(int q=0;q<3;q++){
      float4 v = *(const float4*)(rp + l*4 + q*256);
      sm += v.x + v.y + v.z + v.w;
      sq += v.x*v.x + v.y*v.y + v.z*v.z + v.w*v.w;
    }
    #pragma unroll
    for(int o=32;o>0;o>>=1){ sm += __shfl_xor(sm, o); sq += __shfl_xor(sq, o); }
    if(l == 0){
      float mu = sm * (1.0f/768.0f);
      float var = sq * (1.0f/768.0f) - mu*mu;
      sMu[row] = mu;
      sRs[row] = 1.0f/(sqrtf(var + 1e-12f) + 1e-12f);
    }
  }
  __syncthreads();
  const int mf = w >> 1, nb = (w & 1)*4;             // wave -> (16-row half, col group)
  const int lrow = mf*16 + (l & 15);
  const float mu = sMu[lrow], rs = sRs[lrow];
  const float* aeb = embed + ((long)b*512 + s0 + lrow)*768;   // this lane's A row
  const float* wvb = g_wv + b*768;
  const float* bvb = g_bv + b*768;
  floatx4 acc[4];
  #pragma unroll
  for(int q=0;q<4;q++){ acc[q][0]=0.f; acc[q][1]=0.f; acc[q][2]=0.f; acc[q][3]=0.f; }
  for(int ks=0; ks<24; ++ks){
    const int k = ks*32 + ((l >> 4)*8);
    float4 xlo = *(const float4*)(aeb + k);
    float4 xhi = *(const float4*)(aeb + k + 4);
    float4 wlo = *(const float4*)(wvb + k);
    float4 whi = *(const float4*)(wvb + k + 4);
    float4 clo = *(const float4*)(bvb + k);
    float4 chi = *(const float4*)(bvb + k + 4);
    bhalf8 a;
    a[0]=(short)f2bf((xlo.x - mu)*rs*wlo.x + clo.x);
    a[1]=(short)f2bf((xlo.y - mu)*rs*wlo.y + clo.y);
    a[2]=(short)f2bf((xlo.z - mu)*rs*wlo.z + clo.z);
    a[3]=(short)f2bf((xlo.w - mu)*rs*wlo.w + clo.w);
    a[4]=(short)f2bf((xhi.x - mu)*rs*whi.x + chi.x);
    a[5]=(short)f2bf((xhi.y - mu)*rs*whi.y + chi.y);
    a[6]=(short)f2bf((xhi.z - mu)*rs*whi.z + chi.z);
    a[7]=(short)f2bf((xhi.w - mu)*rs*whi.w + chi.w);
    #pragma unroll
    for(int q=0;q<4;q++){
      const int row = (nb + q)*16 + (l & 15);
      bhalf8 bb = *(const bhalf8*)(g_whl + (long)row*768 + k);
      acc[q] = __builtin_amdgcn_mfma_f32_16x16x32_bf16(a, bb, acc[q], 0, 0, 0);
    }
  }
  const long HT = (long)64*512*51;
  #pragma unroll
  for(int q=0;q<4;q++){
    const int n = (nb + q)*16 + (l & 15);
    if(n >= 102) continue;
    const int rr = (n < 51) ? n : (n - 51);
    const long obase = (n < 51) ? 0 : HT;
    const float bias = (n < 51) ? g_bh[n] : g_bt[n - 51];
    #pragma unroll
    for(int r=0;r<4;r++){
      const int s = s0 + mf*16 + (l >> 4)*4 + r;
      out[obase + ((long)b*512 + s)*51 + rr] = sigm(acc[q][r] + bias);
    }
  }
}

extern "C" void kernel_launch(void* const* d_in, const int* in_sizes, int n_in,
                              void* d_out, int out_size, void* d_ws, size_t ws_size,
                              hipStream_t stream){
  const float* embed = (const float*)d_in[0];
  const int*   head  = (const int*)d_in[1];
  const int*   tail  = (const int*)d_in[2];
  const float* W_ih  = (const float*)d_in[3];
  const float* W_hh  = (const float*)d_in[4];
  const float* b_ih  = (const float*)d_in[5];
  const float* b_hh  = (const float*)d_in[6];
  const float* cw    = (const float*)d_in[7];
  const float* cb    = (const float*)d_in[8];
  const float* Ww    = (const float*)d_in[9];
  const float* Wb    = (const float*)d_in[10];
  const float* Wh    = (const float*)d_in[11];
  const float* bh    = (const float*)d_in[12];
  const float* Wt    = (const float*)d_in[13];
  const float* bt    = (const float*)d_in[14];
  float* out = (float*)d_out;
  (void)d_ws; (void)ws_size;

  casrel_prep<<<dim3(2048), dim3(256), 0, stream>>>(W_ih, W_hh, Ww, Wb, Wh, Wt,
                                                    b_ih, b_hh, cw, cb, bh, bt);
  casrel_xgates<<<dim3(24,16), dim3(256), 0, stream>>>(embed, head);
  for(int t=0; t<16; ++t)
    casrel_step<<<dim3(48), dim3(256), 0, stream>>>(head, tail, t);
  casrel_clnproj<<<dim3(48), dim3(256), 0, stream>>>();
  casrel_out<<<dim3(16,64), dim3(256), 0, stream>>>(embed, out);
}

// Round 25
// 245.262 us; speedup vs baseline: 1.9648x; 1.3277x over previous
//
#include <hip/hip_runtime.h>

typedef __attribute__((ext_vector_type(8))) short bhalf8;
typedef __attribute__((ext_vector_type(4))) float floatx4;

// ---- device-global scratch ----
__device__ unsigned short g_whh[3072*768];     // bf16 W_hh
__device__ unsigned short g_wih[3072*768];     // bf16 W_ih
__device__ unsigned short g_wcln[1536*768];    // bf16 [Ww;Wb]
__device__ unsigned short g_whl[128*768];      // bf16 [Wh;Wt;pad]
__device__ unsigned short g_h2[2*64*768];      // bf16 h ping-pong
__device__ float g_cbuf[64*768];               // f32 c
__device__ float g_xg[16*64*3072];             // f32 xgates, STEP-MAJOR [t][b][3072]
__device__ float g_wv[64*768], g_bv[64*768];   // f32 CLN w,b
__device__ float g_bias[3072];                 // b_ih + b_hh
__device__ float g_cw[768], g_cb[768];
__device__ float g_bh[64], g_bt[64];

static __device__ __forceinline__ unsigned short f2bf(float f){
  unsigned u = __builtin_bit_cast(unsigned, f);
  u = (u + 0x7FFFu + ((u >> 16) & 1u)) >> 16;
  return (unsigned short)u;
}
static __device__ __forceinline__ float sigm(float x){ return 1.0f/(1.0f + __expf(-x)); }
static __device__ __forceinline__ float tanhq(float x){ float e = __expf(-2.0f*x); return (1.0f - e)/(1.0f + e); }

static __device__ __forceinline__ void cv8(const float* __restrict__ s, unsigned short* __restrict__ d){
  float4 a = ((const float4*)s)[0];
  float4 b = ((const float4*)s)[1];
  uint4 v;
  v.x = (unsigned)f2bf(a.x) | ((unsigned)f2bf(a.y) << 16);
  v.y = (unsigned)f2bf(a.z) | ((unsigned)f2bf(a.w) << 16);
  v.z = (unsigned)f2bf(b.x) | ((unsigned)f2bf(b.y) << 16);
  v.w = (unsigned)f2bf(b.z) | ((unsigned)f2bf(b.w) << 16);
  *(uint4*)d = v;
}

// ---------------- K0: vectorized weight conversions + init ----------------
__global__ __launch_bounds__(256) void casrel_prep(
    const float* __restrict__ W_ih, const float* __restrict__ W_hh,
    const float* __restrict__ Ww,   const float* __restrict__ Wb,
    const float* __restrict__ Wh,   const float* __restrict__ Wt,
    const float* __restrict__ b_ih, const float* __restrict__ b_hh,
    const float* __restrict__ cw,   const float* __restrict__ cb,
    const float* __restrict__ bh,   const float* __restrict__ bt){
  const long CW = 294912;            // 3072*768/8
  const long CC = 147456;            // 1536*768/8
  const long CL = 12288;             // 128*768/8
  const long CH = 12288;             // 2*64*768/8
  const long CF = 6144;              // 64*768/8 (cbuf f32)
  const long CB = 384, CV = 96, CR = 8;
  const long total = CW*2 + CC + CL + CH + CF + CB + CV*2 + CR*2;
  for(long i = (long)blockIdx.x*256 + threadIdx.x; i < total; i += (long)gridDim.x*256){
    long j = i;
    if(j < CW){ cv8(W_hh + j*8, g_whh + j*8); continue; } j -= CW;
    if(j < CW){ cv8(W_ih + j*8, g_wih + j*8); continue; } j -= CW;
    if(j < CC){ long e = j*8;
                if(e < 589824) cv8(Ww + e, g_wcln + e);
                else           cv8(Wb + (e - 589824), g_wcln + e);
                continue; } j -= CC;
    if(j < CL){ long e = j*8;
                long r = e / 768, k = e - r*768;
                if(r < 51)       cv8(Wh + r*768 + k, g_whl + e);
                else if(r < 102) cv8(Wt + (r-51)*768 + k, g_whl + e);
                else             *(uint4*)(g_whl + e) = make_uint4(0,0,0,0);
                continue; } j -= CL;
    if(j < CH){ *(uint4*)(g_h2 + j*8) = make_uint4(0,0,0,0); continue; } j -= CH;
    if(j < CF){ long e = j*8;
                *(float4*)(g_cbuf + e)     = make_float4(0,0,0,0);
                *(float4*)(g_cbuf + e + 4) = make_float4(0,0,0,0);
                continue; } j -= CF;
    if(j < CB){ long e = j*8;
                #pragma unroll
                for(int q=0;q<8;q++) g_bias[e+q] = b_ih[e+q] + b_hh[e+q];
                continue; } j -= CB;
    if(j < CV){ long e = j*8;
                *(float4*)(g_cw + e)     = *(const float4*)(cw + e);
                *(float4*)(g_cw + e + 4) = *(const float4*)(cw + e + 4);
                continue; } j -= CV;
    if(j < CV){ long e = j*8;
                *(float4*)(g_cb + e)     = *(const float4*)(cb + e);
                *(float4*)(g_cb + e + 4) = *(const float4*)(cb + e + 4);
                continue; } j -= CV;
    if(j < CR){ long e = j*8;
                #pragma unroll
                for(int q=0;q<8;q++){ long n = e+q; g_bh[n] = (n < 51) ? bh[n] : 0.0f; }
                continue; } j -= CR;
    { long e = j*8;
      #pragma unroll
      for(int q=0;q<8;q++){ long n = e+q; g_bt[n] = (n < 51) ? bt[n] : 0.0f; } }
  }
}

// ---------------- K1: xgates -> STEP-MAJOR layout [t][b][3072] ----------------
__global__ __launch_bounds__(256) void casrel_xgates(
    const float* __restrict__ embed, const int* __restrict__ head){
  __shared__ char sB[128*128];
  const int tid = threadIdx.x, l = tid & 63, w = tid >> 6;
  const int n0 = blockIdx.x * 128;
  const int m0 = blockIdx.y * 64 + w*16;
  const int mrow = m0 + (l & 15);
  const int b = mrow >> 4, t = mrow & 15;
  int pos = head[b] + t; pos = pos < 0 ? 0 : (pos > 511 ? 511 : pos);
  const float* aptr = embed + ((long)b*512 + pos)*768 + ((l >> 4)*8);
  floatx4 acc[8];
  #pragma unroll
  for(int q=0;q<8;q++){ acc[q][0]=0.f; acc[q][1]=0.f; acc[q][2]=0.f; acc[q][3]=0.f; }
  for(int kt=0; kt<12; ++kt){
    __syncthreads();
    #pragma unroll
    for(int j=0;j<4;j++){
      int f = tid + 256*j;
      int row = f >> 3, seg = f & 7;
      uint4 v = *(const uint4*)(g_wih + ((long)(n0+row))*768 + kt*64 + seg*8);
      *(uint4*)(sB + row*128 + ((seg*16) ^ ((row & 7) << 4))) = v;
    }
    __syncthreads();
    #pragma unroll
    for(int ks=0; ks<2; ++ks){
      const int k = kt*64 + ks*32;
      float4 lo = *(const float4*)(aptr + k);
      float4 hi = *(const float4*)(aptr + k + 4);
      bhalf8 a;
      a[0]=(short)f2bf(lo.x); a[1]=(short)f2bf(lo.y); a[2]=(short)f2bf(lo.z); a[3]=(short)f2bf(lo.w);
      a[4]=(short)f2bf(hi.x); a[5]=(short)f2bf(hi.y); a[6]=(short)f2bf(hi.z); a[7]=(short)f2bf(hi.w);
      const int kb = ks*64 + ((l >> 4)*16);
      #pragma unroll
      for(int q=0;q<8;q++){
        int row = q*16 + (l & 15);
        bhalf8 bb = *(const bhalf8*)(sB + row*128 + (kb ^ ((row & 7) << 4)));
        acc[q] = __builtin_amdgcn_mfma_f32_16x16x32_bf16(a, bb, acc[q], 0, 0, 0);
      }
    }
  }
  #pragma unroll
  for(int q=0;q<8;q++){
    const int n = n0 + q*16 + (l & 15);
    const float bias = g_bias[n];
    #pragma unroll
    for(int r=0;r<4;r++){
      const int m = m0 + (l >> 4)*4 + r;
      const int bb2 = m >> 4, tt = m & 15;
      g_xg[((long)(tt*64 + bb2))*3072 + n] = acc[q][r] + bias;
    }
  }
}

// ---------------- K2a: one LSTM step — 96 blocks x 8 cols, 1 barrier, shfl gate-gather ----------------
// Block bk owns h-cols [bk*8, bk*8+8) across 4 gates -> 32 LDS rows [gate][col], full K.
__global__ __launch_bounds__(256) void casrel_step(
    const int* __restrict__ head, const int* __restrict__ tail, int t){
  __shared__ char sW[32*1536];                       // 32 rows x 768 bf16, swizzled (48KB)
  const unsigned short* hin = g_h2 + (t & 1)*49152;
  unsigned short* hout = g_h2 + ((t & 1) ^ 1)*49152;
  const int tid = threadIdx.x, l = tid & 63, w = tid >> 6;
  const int j0 = blockIdx.x * 8;
  #pragma unroll
  for(int j=0;j<12;j++){                             // stage 32 rows x 96 segs of 16B
    int f = tid + 256*j;
    int row = f / 96, seg = f - row*96;
    int grow = (row >> 3)*768 + j0 + (row & 7);      // gate = row>>3, col = row&7
    uint4 v = *(const uint4*)(g_whh + (long)grow*768 + seg*8);
    *(uint4*)(sW + row*1536 + ((seg*16) ^ ((row & 7) << 4))) = v;
  }
  __syncthreads();
  const int arow = w*16 + (l & 15);
  floatx4 acc[2];
  #pragma unroll
  for(int q=0;q<2;q++){ acc[q][0]=0.f; acc[q][1]=0.f; acc[q][2]=0.f; acc[q][3]=0.f; }
  const unsigned short* ap = hin + arow*768 + ((l >> 4)*8);
  #pragma unroll 6
  for(int ks=0; ks<24; ++ks){
    bhalf8 a = *(const bhalf8*)(ap + ks*32);
    const int kb = ks*64 + ((l >> 4)*16);
    #pragma unroll
    for(int q=0;q<2;q++){
      int row = q*16 + (l & 15);
      bhalf8 bb = *(const bhalf8*)(sW + row*1536 + (kb ^ ((row & 7) << 4)));
      acc[q] = __builtin_amdgcn_mfma_f32_16x16x32_bf16(a, bb, acc[q], 0, 0, 0);
    }
  }
  // epilogue: lane n16=l&15: acc[0] = gate(n16>>3) col(n16&7); acc[1] = gate(2+(n16>>3)).
  // lanes n16<8 hold {i,g}; lanes n16>=8 hold {f,o} for the SAME col -> shfl_xor(8).
  const int c = l & 7;
  const int jown = j0 + c;
  const bool lo = (l & 8) == 0;
  #pragma unroll
  for(int r=0;r<4;r++){
    const int b = w*16 + (l >> 4)*4 + r;
    float v0 = acc[0][r], v1 = acc[1][r];
    float o0 = __shfl_xor(v0, 8);
    float o1 = __shfl_xor(v1, 8);
    if(lo){
      const int cell = b*768 + jown;
      const float* xp = g_xg + ((long)(t*64 + b))*3072 + jown;
      float Gi = v0 + xp[0];
      float Gf = o0 + xp[768];
      float Gg = v1 + xp[1536];
      float Go = o1 + xp[2304];
      if(t <= tail[b] - head[b]){
        float cc = g_cbuf[cell];
        float ig = sigm(Gi), fg = sigm(Gf), gg = tanhq(Gg), og = sigm(Go);
        cc = fg*cc + ig*gg;
        g_cbuf[cell] = cc;
        hout[cell] = f2bf(og*tanhq(cc));
      } else {
        hout[cell] = hin[cell];
      }
    }
  }
}

// ---------------- K2b: wv = hn@Ww^T + cw ; bv = hn@Wb^T + cb ----------------
__global__ __launch_bounds__(256) void casrel_clnproj(){
  __shared__ char sW[32*1536];
  const int tid = threadIdx.x, l = tid & 63, w = tid >> 6;
  const int n0c = blockIdx.x * 32;
  #pragma unroll
  for(int j=0;j<12;j++){
    int f = tid + 256*j;
    int row = f / 96, seg = f - row*96;
    uint4 v = *(const uint4*)(g_wcln + (long)(n0c+row)*768 + seg*8);
    *(uint4*)(sW + row*1536 + ((seg*16) ^ ((row & 7) << 4))) = v;
  }
  __syncthreads();
  const int arow = w*16 + (l & 15);
  floatx4 acc2[2];
  #pragma unroll
  for(int q=0;q<2;q++){ acc2[q][0]=0.f; acc2[q][1]=0.f; acc2[q][2]=0.f; acc2[q][3]=0.f; }
  const unsigned short* ap2 = g_h2 + arow*768 + ((l >> 4)*8);   // buf 0 = final h
  for(int ks=0; ks<24; ++ks){
    bhalf8 a = *(const bhalf8*)(ap2 + ks*32);
    const int kb = ks*64 + ((l >> 4)*16);
    #pragma unroll
    for(int q=0;q<2;q++){
      int row = q*16 + (l & 15);
      bhalf8 bb = *(const bhalf8*)(sW + row*1536 + (kb ^ ((row & 7) << 4)));
      acc2[q] = __builtin_amdgcn_mfma_f32_16x16x32_bf16(a, bb, acc2[q], 0, 0, 0);
    }
  }
  #pragma unroll
  for(int q=0;q<2;q++){
    const int n = n0c + q*16 + (l & 15);
    #pragma unroll
    for(int r=0;r<4;r++){
      const int b = w*16 + (l >> 4)*4 + r;
      float v = acc2[q][r];
      if(n < 768) g_wv[b*768 + n] = v + g_cw[n];
      else        g_bv[b*768 + (n - 768)] = v + g_cb[n - 768];
    }
  }
}

// ---------------- K3: fused cond-LN + heads/tails (r22 LDS-staged version, f32 out) ----------------
__global__ __launch_bounds__(256) void casrel_out(
    const float* __restrict__ embed, float* __restrict__ out){
  __shared__ char sB[128*128];
  __shared__ char sE[32*128];
  __shared__ float sMu[32], sRs[32];
  const int tid = threadIdx.x, l = tid & 63, w = tid >> 6;
  const int b = blockIdx.y;
  const int s0 = blockIdx.x * 32;
  const float* xbase = embed + ((long)b*512 + s0)*768;
  for(int rr=0; rr<8; ++rr){
    const int row = w*8 + rr;
    const float* rp = xbase + row*768;
    float sm = 0.f, sq = 0.f;
    #pragma unroll
    for(int q=0;q<3;q++){
      float4 v = *(const float4*)(rp + l*4 + q*256);
      sm += v.x + v.y + v.z + v.w;
      sq += v.x*v.x + v.y*v.y + v.z*v.z + v.w*v.w;
    }
    #pragma unroll
    for(int o=32;o>0;o>>=1){ sm += __shfl_xor(sm, o); sq += __shfl_xor(sq, o); }
    if(l == 0){
      float mu = sm * (1.0f/768.0f);
      float var = sq * (1.0f/768.0f) - mu*mu;
      sMu[row] = mu;
      sRs[row] = 1.0f/(sqrtf(var + 1e-12f) + 1e-12f);
    }
  }
  __syncthreads();
  const int mf = w >> 1, nb = (w & 1)*4;
  floatx4 acc[4];
  #pragma unroll
  for(int q=0;q<4;q++){ acc[q][0]=0.f; acc[q][1]=0.f; acc[q][2]=0.f; acc[q][3]=0.f; }
  for(int kt=0; kt<12; ++kt){
    __syncthreads();
    #pragma unroll
    for(int j=0;j<4;j++){
      int f = tid + 256*j;
      int row = f >> 3, seg = f & 7;
      uint4 v = *(const uint4*)(g_whl + (long)row*768 + kt*64 + seg*8);
      *(uint4*)(sB + row*128 + ((seg*16) ^ ((row & 7) << 4))) = v;
    }
    #pragma unroll
    for(int j=0;j<2;j++){
      int f = tid + 256*j;
      int row = f >> 4, cs = f & 15;
      int k = kt*64 + cs*4;
      float4 x4 = *(const float4*)(xbase + row*768 + k);
      float4 w4 = *(const float4*)(g_wv + b*768 + k);
      float4 c4 = *(const float4*)(g_bv + b*768 + k);
      float mu = sMu[row], rs = sRs[row];
      unsigned long long pk =
          (unsigned long long)f2bf((x4.x - mu)*rs*w4.x + c4.x)
        | ((unsigned long long)f2bf((x4.y - mu)*rs*w4.y + c4.y) << 16)
        | ((unsigned long long)f2bf((x4.z - mu)*rs*w4.z + c4.z) << 32)
        | ((unsigned long long)f2bf((x4.w - mu)*rs*w4.w + c4.w) << 48);
      *(unsigned long long*)(sE + row*128 + ((cs*8) ^ ((row & 7) << 4))) = pk;
    }
    __syncthreads();
    #pragma unroll
    for(int ks=0; ks<2; ++ks){
      const int arow = mf*16 + (l & 15);
      const int kb = ks*64 + ((l >> 4)*16);
      bhalf8 a = *(const bhalf8*)(sE + arow*128 + (kb ^ ((arow & 7) << 4)));
      #pragma unroll
      for(int q=0;q<4;q++){
        int row = (nb + q)*16 + (l & 15);
        bhalf8 bb = *(const bhalf8*)(sB + row*128 + (kb ^ ((row & 7) << 4)));
        acc[q] = __builtin_amdgcn_mfma_f32_16x16x32_bf16(a, bb, acc[q], 0, 0, 0);
      }
    }
  }
  const long HT = (long)64*512*51;
  #pragma unroll
  for(int q=0;q<4;q++){
    const int n = (nb + q)*16 + (l & 15);
    if(n >= 102) continue;
    const int rr = (n < 51) ? n : (n - 51);
    const long obase = (n < 51) ? 0 : HT;
    const float bias = (n < 51) ? g_bh[n] : g_bt[n - 51];
    #pragma unroll
    for(int r=0;r<4;r++){
      const int s = s0 + mf*16 + (l >> 4)*4 + r;
      out[obase + ((long)b*512 + s)*51 + rr] = sigm(acc[q][r] + bias);
    }
  }
}

extern "C" void kernel_launch(void* const* d_in, const int* in_sizes, int n_in,
                              void* d_out, int out_size, void* d_ws, size_t ws_size,
                              hipStream_t stream){
  const float* embed = (const float*)d_in[0];
  const int*   head  = (const int*)d_in[1];
  const int*   tail  = (const int*)d_in[2];
  const float* W_ih  = (const float*)d_in[3];
  const float* W_hh  = (const float*)d_in[4];
  const float* b_ih  = (const float*)d_in[5];
  const float* b_hh  = (const float*)d_in[6];
  const float* cw    = (const float*)d_in[7];
  const float* cb    = (const float*)d_in[8];
  const float* Ww    = (const float*)d_in[9];
  const float* Wb    = (const float*)d_in[10];
  const float* Wh    = (const float*)d_in[11];
  const float* bh    = (const float*)d_in[12];
  const float* Wt    = (const float*)d_in[13];
  const float* bt    = (const float*)d_in[14];
  float* out = (float*)d_out;
  (void)d_ws; (void)ws_size;

  casrel_prep<<<dim3(2048), dim3(256), 0, stream>>>(W_ih, W_hh, Ww, Wb, Wh, Wt,
                                                    b_ih, b_hh, cw, cb, bh, bt);
  casrel_xgates<<<dim3(24,16), dim3(256), 0, stream>>>(embed, head);
  for(int t=0; t<16; ++t)
    casrel_step<<<dim3(96), dim3(256), 0, stream>>>(head, tail, t);
  casrel_clnproj<<<dim3(48), dim3(256), 0, stream>>>();
  casrel_out<<<dim3(16,64), dim3(256), 0, stream>>>(embed, out);
}